// Round 11
// baseline (642.387 us; speedup 1.0000x reference)
//
#include <hip/hip_runtime.h>

typedef unsigned short u16;
typedef unsigned int u32;
using short8  = __attribute__((ext_vector_type(8))) short;
using floatx4 = __attribute__((ext_vector_type(4))) float;

#define NB 32
#define SEQ 1024
#define EMB 512
#define NH 8
#define HD 64
#define NLAYER 2
#define M_ROWS (NB * SEQ)   // 32768

__device__ __forceinline__ float bf2f(u16 u) {
  union { u32 i; float f; } v; v.i = ((u32)u) << 16; return v.f;
}
__device__ __forceinline__ u16 f2bf(float f) {
  union { float f; u32 i; } v; v.f = f;
  u32 r = v.i + 0x7fffu + ((v.i >> 16) & 1u);
  return (u16)(r >> 16);
}
// packed f32x2 -> bf16x2 (RNE, same as f2bf). lo16 = cvt(a), hi16 = cvt(b).
__device__ __forceinline__ u32 cvtpk(float a, float b) {
  u32 r;
  asm volatile("v_cvt_pk_bf16_f32 %0, %1, %2" : "=v"(r) : "v"(a), "v"(b));
  return r;
}

#if __has_builtin(__builtin_amdgcn_exp2f)
#define EXP2F __builtin_amdgcn_exp2f
#else
#define EXP2F exp2f
#endif

// async global->LDS, 16B per lane. LDS dest = wave-uniform base + lane*16.
typedef __attribute__((address_space(3))) unsigned int lds_u32_t;
typedef __attribute__((address_space(1))) const unsigned int gbl_u32_t;
__device__ __forceinline__ void gload16(void* lds, const void* g) {
  gbl_u32_t* gp = (gbl_u32_t*)(unsigned long long)g;
  lds_u32_t* lp = (lds_u32_t*)(unsigned int)(unsigned long long)lds;
  __builtin_amdgcn_global_load_lds(gp, lp, 16, 0, 0);
}

// ---------------- weight pre-transpose + fp32->bf16: W[K,N] -> Bt[N,K] ------
__global__ void prep_weights(const float* __restrict__ Wq, const float* __restrict__ Wk,
                             const float* __restrict__ Wv, const float* __restrict__ Wo,
                             u16* __restrict__ WtQKV, u16* __restrict__ WtO) {
  int idx = blockIdx.x * 256 + threadIdx.x;
  const int QKV_TOT = NLAYER * 3 * EMB * EMB;
  if (idx < QKV_TOT) {
    int l = idx / (3 * EMB * EMB);
    int rem = idx % (3 * EMB * EMB);
    int n = rem / EMB, kk = rem % EMB;
    int w = n >> 9, e = n & 511;
    const float* src = (w == 0) ? Wq : (w == 1) ? Wk : Wv;
    WtQKV[idx] = f2bf(src[((size_t)l * EMB + kk) * EMB + e]);
  } else {
    int j = idx - QKV_TOT;
    int l = j / (EMB * EMB);
    int rem = j % (EMB * EMB);
    int n = rem / EMB, kk = rem % EMB;
    WtO[j] = f2bf(Wo[((size_t)l * EMB + kk) * EMB + n]);
  }
}

// ---------------- positional-encoding table: pe[s][e], f32 ------------------
__global__ void pe_table(float* __restrict__ pe) {
  int idx = blockIdx.x * 256 + threadIdx.x;
  int s = idx >> 9, e = idx & 511;
  int i = e >> 1;
  const float negln = -9.210340371976184f / (float)EMB;
  float dt = __expf((float)(2 * i) * negln);
  float ang = (float)s * dt;
  pe[idx] = (e & 1) ? __cosf(ang) : __sinf(ang);
}

// ---------------- embedding + PE add (gather + add + pack, no trig) ---------
__global__ void embed_pe(const int* __restrict__ inp, const float* __restrict__ table,
                         const float* __restrict__ pe, u16* __restrict__ x) {
  int row = blockIdx.x;
  int tok = inp[row];
  int s = row & (SEQ - 1);
  int e = threadIdx.x * 2;
  float2 tv = *(const float2*)&table[(size_t)tok * EMB + e];
  float2 pv = *(const float2*)&pe[(size_t)s * EMB + e];
  *(u32*)&x[(size_t)row * EMB + e] = cvtpk(tv.x + pv.x, tv.y + pv.y);
}

// ---------------- GEMM: C[M,N] = A[M,K] @ Bt[N,K]^T + bias ------------------
// FROZEN r5/r9 state. 128x128, 3 LDS buffers, 2-deep prefetch, vmcnt(8).
// MfmaUtil pinned ~20% across 4 schedule variants; next step (8-phase 256²)
// is a sync-structure rewrite — disqualified headless (r7 raced).
// mode 0: N=1536 (NT=12). Q (*0.125*log2e folded: attn uses exp2), K ->
//         [B,H,S,D]; V (bn0>=1024): operand-swapped MFMA -> [B,H,D,S].
// mode 1: N=512 (NT=4),  x = x + relu(C + bias)  (in place, out0 == resid)
#define BK 32

__global__ __launch_bounds__(256) void gemm_bt(
    const u16* __restrict__ A, const u16* __restrict__ Bt, int K, int mode,
    const float* bias0, const float* bias1, const float* bias2,
    u16* out0, u16* out1, u16* out2, const u16* resid, int Nstride) {
  __shared__ u16 sA[3][128][BK];
  __shared__ u16 sB[3][128][BK];
  int tid = threadIdx.x;
  int wave = tid >> 6, lane = tid & 63;
  int quad = lane >> 4, l16 = lane & 15;
  int wm = wave >> 1, wn = wave & 1;

  int NT = (mode == 0) ? 12 : 4;          // N-tiles per M-tile
  int blk = blockIdx.x;
  int xcd = blk & 7, slot = blk >> 3;
  int mtl = slot / NT, ntl = slot % NT;   // 32 M-tiles per XCD, N-tiles inner
  int bm0 = (xcd * 32 + mtl) * 128;
  int bn0 = ntl * 128;
  bool vswap = (mode == 0) && (bn0 >= 1024);

  floatx4 acc[4][4];
#pragma unroll
  for (int i = 0; i < 4; ++i)
#pragma unroll
    for (int j = 0; j < 4; ++j) acc[i][j] = (floatx4){0.f, 0.f, 0.f, 0.f};

  int rb = wave * 32;                         // wave stages rows rb..rb+31
  int lrow = lane >> 2;                       // 0..15
  int gcg = ((lane & 3) ^ ((lane >> 3) & 3)) * 8;  // fetch chunk for slot lane&3
  int rsl = (quad ^ ((l16 >> 1) & 3)) * 8;    // read slot holding chunk `quad`

  const u16* Arow0 = &A[(size_t)(bm0 + rb + lrow) * K + gcg];
  const u16* Arow1 = &A[(size_t)(bm0 + rb + 16 + lrow) * K + gcg];
  const u16* Brow0 = &Bt[(size_t)(bn0 + rb + lrow) * K + gcg];
  const u16* Brow1 = &Bt[(size_t)(bn0 + rb + 16 + lrow) * K + gcg];

  // prologue: stage k-tiles 0,1 into buffers 0,1 (niter is always 16 here)
  gload16(&sA[0][rb][0],      Arow0);
  gload16(&sA[0][rb + 16][0], Arow1);
  gload16(&sB[0][rb][0],      Brow0);
  gload16(&sB[0][rb + 16][0], Brow1);
  gload16(&sA[1][rb][0],      Arow0 + BK);
  gload16(&sA[1][rb + 16][0], Arow1 + BK);
  gload16(&sB[1][rb][0],      Brow0 + BK);
  gload16(&sB[1][rb + 16][0], Brow1 + BK);

  const int niter = K / BK;
  int c0 = 0, c1 = 1, c2 = 2;   // c0 = compute buf, c2 = stage target
  for (int it = 0; it < niter; ++it) {
    if (it + 2 < niter) {
      int k2 = (it + 2) * BK;
      gload16(&sA[c2][rb][0],      Arow0 + k2);
      gload16(&sA[c2][rb + 16][0], Arow1 + k2);
      gload16(&sB[c2][rb][0],      Brow0 + k2);
      gload16(&sB[c2][rb + 16][0], Brow1 + k2);
      asm volatile("s_waitcnt vmcnt(8)" ::: "memory");  // tile `it` complete
    } else if (it + 1 < niter) {
      asm volatile("s_waitcnt vmcnt(4)" ::: "memory");  // tile `it` complete
    } else {
      asm volatile("s_waitcnt vmcnt(0)" ::: "memory");
    }
    asm volatile("s_barrier" ::: "memory");             // buf ready for all

    short8 af[4], bfr[4];
#pragma unroll
    for (int mi = 0; mi < 4; ++mi)
      af[mi] = *(const short8*)&sA[c0][wm * 64 + mi * 16 + l16][rsl];
#pragma unroll
    for (int ni = 0; ni < 4; ++ni)
      bfr[ni] = *(const short8*)&sB[c0][wn * 64 + ni * 16 + l16][rsl];
    if (!vswap) {
#pragma unroll
      for (int mi = 0; mi < 4; ++mi)
#pragma unroll
        for (int ni = 0; ni < 4; ++ni)
          acc[mi][ni] = __builtin_amdgcn_mfma_f32_16x16x32_bf16(af[mi], bfr[ni], acc[mi][ni], 0, 0, 0);
    } else {
#pragma unroll
      for (int mi = 0; mi < 4; ++mi)
#pragma unroll
        for (int ni = 0; ni < 4; ++ni)
          acc[mi][ni] = __builtin_amdgcn_mfma_f32_16x16x32_bf16(bfr[ni], af[mi], acc[mi][ni], 0, 0, 0);
    }
    asm volatile("s_waitcnt lgkmcnt(0)" ::: "memory");  // all ds_reads complete
    asm volatile("s_barrier" ::: "memory");             // before buf overwrite
    int t = c0; c0 = c1; c1 = c2; c2 = t;
  }

  // ---- epilogue: wave-private LDS repack -> coalesced 128B dword-row stores
  u16* scr = ((u16*)sA) + wave * (16 * 68);
  int erow = lane >> 5;            // 0..1: row within a read pass
  int dcol = lane & 31;            // dword column (2 bf16 per dword)

  if (!vswap) {
    int w = bn0 >> 9;                                   // 0=Q, 1=K (mode 0)
    const float* bp = (mode == 1) ? bias0 : ((w == 0) ? bias0 : bias1);
    // Q: fold 1/sqrt(D) AND log2(e) so attn can use v_exp_f32 (exp2) directly
    float sc = (mode == 0 && w == 0) ? 0.18033688011112042f : 1.0f;
    float bvs[4];
#pragma unroll
    for (int ni = 0; ni < 4; ++ni)
      bvs[ni] = bp[(bn0 + wn * 64 + ni * 16 + l16) & 511] * sc;

    int colg = bn0 + wn * 64 + dcol * 2;
#pragma unroll
    for (int mi = 0; mi < 4; ++mi) {
#pragma unroll
      for (int ni = 0; ni < 4; ++ni) {
        float t0 = fmaf(acc[mi][ni][0], sc, bvs[ni]);
        float t1 = fmaf(acc[mi][ni][1], sc, bvs[ni]);
        float t2 = fmaf(acc[mi][ni][2], sc, bvs[ni]);
        float t3 = fmaf(acc[mi][ni][3], sc, bvs[ni]);
        if (mode == 1) {
          t0 = fmaxf(t0, 0.f); t1 = fmaxf(t1, 0.f);
          t2 = fmaxf(t2, 0.f); t3 = fmaxf(t3, 0.f);
        }
        u32 p01 = cvtpk(t0, t1), p23 = cvtpk(t2, t3);
        int base = (quad * 4) * 68 + ni * 16 + l16;
        scr[base]       = (u16)p01;
        scr[base + 68]  = (u16)(p01 >> 16);
        scr[base + 136] = (u16)p23;
        scr[base + 204] = (u16)(p23 >> 16);
      }
      asm volatile("s_waitcnt lgkmcnt(0)" ::: "memory");  // wave-private: no barrier

      int m0 = bm0 + wm * 64 + mi * 16;
      if (mode == 0) {
        // Q/K store: [B,H,S,D]; rows m0..m0+15 share b,h; sid,addr linear in row
        int e = colg & 511, hh = e >> 6, dd = e & 63;
        int bb = m0 >> 10, sid0 = m0 & 1023;
        u16* optr = (w == 0) ? out0 : out1;
        u16* op = &optr[((size_t)(bb * NH + hh) * SEQ + sid0) * HD + dd];
#pragma unroll
        for (int p = 0; p < 8; ++p) {
          int row = p * 2 + erow;
          u32 d2 = *(const u32*)&scr[row * 68 + dcol * 2];
          *(u32*)&op[(size_t)row * HD] = d2;
        }
      } else {
        size_t off0 = (size_t)m0 * Nstride + colg;
        const u16* rp = &resid[off0];
        u16* wp = &out0[off0];
#pragma unroll
        for (int p = 0; p < 8; ++p) {
          int row = p * 2 + erow;
          u32 d2 = *(const u32*)&scr[row * 68 + dcol * 2];
          u32 rs = *(const u32*)&rp[(size_t)row * Nstride];
          float lo = bf2f((u16)d2) + bf2f((u16)rs);
          float hi = bf2f((u16)(d2 >> 16)) + bf2f((u16)(rs >> 16));
          *(u32*)&wp[(size_t)row * Nstride] = cvtpk(lo, hi);
        }
      }
      asm volatile("s_waitcnt lgkmcnt(0)" ::: "memory");  // reads done before rewrite
    }
  } else {
    // V section: D rows = weight rows (d), D cols = x rows (sid)
    float bvv[4][4];
#pragma unroll
    for (int ni = 0; ni < 4; ++ni)
#pragma unroll
      for (int r = 0; r < 4; ++r)
        bvv[ni][r] = bias2[(bn0 + wn * 64 + ni * 16 + quad * 4 + r) & 511];

    int b = (bm0 + wm * 64) >> 10;
    int sid0 = (bm0 + wm * 64) & 1023;
    int n0 = bn0 + wn * 64;
    int h = (n0 >> 6) & 7;
#pragma unroll
    for (int ni = 0; ni < 4; ++ni) {
#pragma unroll
      for (int mi = 0; mi < 4; ++mi) {
        float t0 = acc[mi][ni][0] + bvv[ni][0];
        float t1 = acc[mi][ni][1] + bvv[ni][1];
        float t2 = acc[mi][ni][2] + bvv[ni][2];
        float t3 = acc[mi][ni][3] + bvv[ni][3];
        u32 p01 = cvtpk(t0, t1), p23 = cvtpk(t2, t3);
        int base = (quad * 4) * 68 + mi * 16 + l16;
        scr[base]       = (u16)p01;
        scr[base + 68]  = (u16)(p01 >> 16);
        scr[base + 136] = (u16)p23;
        scr[base + 204] = (u16)(p23 >> 16);
      }
      asm volatile("s_waitcnt lgkmcnt(0)" ::: "memory");

      int d0 = (n0 & 63) + ni * 16;
      u16* op2 = &out2[((size_t)(b * NH + h) * HD + d0) * SEQ + sid0 + dcol * 2];
#pragma unroll
      for (int p = 0; p < 8; ++p) {
        int row = p * 2 + erow;
        u32 d2 = *(const u32*)&scr[row * 68 + dcol * 2];
        *(u32*)&op2[(size_t)row * SEQ] = d2;
      }
      asm volatile("s_waitcnt lgkmcnt(0)" ::: "memory");
    }
  }
}

// ---------------- flash attention, causal ----------------------------------
// MERGED K-LOOP (r10) + 2 K/V TILES PER BARRIER PAIR: sP collapsed 4 slots ->
// 1 (r2-proven wave-private WAR: leading wave-local lgkmcnt(0) before the
// P-writes; no barrier), freed LDS buys sK[2]/sV[2] so each __syncthreads
// pair stages TWO tiles (8 loads/wave) and processes both. Tiles per block
// 2*qL+2 is always even -> pairing exact; barrier pairs 13avg -> 5.5avg
// (-58% of the serial stage->drain chain). Sync semantics unchanged from
// r5/r10 (same __syncthreads pairs, bigger batches). LDS 41472 B, 3 blk/CU.
// Q fragments direct global->reg; Q pre-scaled 0.125*log2e -> p = exp2(s);
// causal cndmasks only on the wave-uniform diagonal tile.
__device__ __forceinline__ void stage_tile64(u16 (*dst)[64], const u16* g, int gstride,
                                             int wave, int lane) {
  int r = lane >> 3;
  int gcg = ((lane & 7) ^ r) * 8;
#pragma unroll
  for (int c = 0; c < 2; ++c) {
    int row0 = (wave * 2 + c) * 8;
    gload16(&dst[row0][0], &g[(size_t)(row0 + r) * gstride + gcg]);
  }
}
#define RD8(T, row, cg) (*(const short8*)&T[row][(((cg) ^ ((row) & 7)) * 8)])

__global__ __launch_bounds__(256) void attn_kernel(
    const u16* __restrict__ q, const u16* __restrict__ k, const u16* __restrict__ vt,
    u16* __restrict__ o) {
  int blk = blockIdx.x;          // 0..1023
  int xcd = blk & 7, slot = blk >> 3;    // slot 0..127
  int bh = xcd * 32 + (slot >> 2);       // 4 pair-blocks per bh, same XCD
  int pr = slot & 3;                     // pair: jobs qtp = pr (short), 7-pr (long)
  int b = bh >> 3, h = bh & 7;
  int qS = pr, qL = 7 - pr;
  int sA0 = qS * 128, sB0 = sA0 + 64;    // short job q-row bases
  int lA0 = qL * 128, lB0 = lA0 + 64;    // long job q-row bases
  __shared__ u16 sK[2][64][64], sV[2][64][64];
  __shared__ u16 sP[64][68];             // single slot, wave-private WAR
  int tid = threadIdx.x, wave = tid >> 6, lane = tid & 63;
  int quad = lane >> 4, l16 = lane & 15;

  const u16* kbase = &k[(size_t)bh * SEQ * HD];
  const u16* vbase = &vt[(size_t)bh * HD * SEQ];

  // direct global->register Q fragments (once per block). Fragment for MFMA
  // A-operand row (wave*16+l16): chunks quad*8 and 32+quad*8 of that row.
  int qrow = wave * 16 + l16;
  const u16* qb_ = &q[((size_t)bh * SEQ + qrow) * HD + quad * 8];
  short8 aqSA0 = *(const short8*)&qb_[(size_t)sA0 * HD];
  short8 aqSA1 = *(const short8*)&qb_[(size_t)sA0 * HD + 32];
  short8 aqSB0 = *(const short8*)&qb_[(size_t)sB0 * HD];
  short8 aqSB1 = *(const short8*)&qb_[(size_t)sB0 * HD + 32];
  short8 aqLA0 = *(const short8*)&qb_[(size_t)lA0 * HD];
  short8 aqLA1 = *(const short8*)&qb_[(size_t)lA0 * HD + 32];
  short8 aqLB0 = *(const short8*)&qb_[(size_t)lB0 * HD];
  short8 aqLB1 = *(const short8*)&qb_[(size_t)lB0 * HD + 32];

  short8 ones;
#pragma unroll
  for (int j = 0; j < 8; ++j) ones[j] = (short)0x3F80;   // bf16 1.0

  floatx4 accSA[4], accSB[4], accLA[4], accLB[4];
  floatx4 sumSA, sumSB, sumLA, sumLB;
#pragma unroll
  for (int i = 0; i < 4; ++i) {
    accSA[i] = (floatx4){0.f, 0.f, 0.f, 0.f};
    accSB[i] = (floatx4){0.f, 0.f, 0.f, 0.f};
    accLA[i] = (floatx4){0.f, 0.f, 0.f, 0.f};
    accLB[i] = (floatx4){0.f, 0.f, 0.f, 0.f};
  }
  sumSA = (floatx4){0.f, 0.f, 0.f, 0.f};
  sumSB = (floatx4){0.f, 0.f, 0.f, 0.f};
  sumLA = (floatx4){0.f, 0.f, 0.f, 0.f};
  sumLB = (floatx4){0.f, 0.f, 0.f, 0.f};

  // one sub-tile pass on staged tile `ts`: S = Q@K^T (pre-scaled incl.
  // log2e), p = exp2(s) (masked->0), P->LDS->A-layout, PV + ones-MFMA sums.
  // sP is a SINGLE slot: leading wave-local lgkmcnt(0) covers the WAR on the
  // previous pass's ap reads (rows are wave-private; r2-proven discipline).
  auto process = [&](short8 aq0, short8 aq1, int qX0, bool diag, int ts,
                     floatx4* acco, floatx4& accsum, int k0) {
    floatx4 accs[4];
#pragma unroll
    for (int i = 0; i < 4; ++i) accs[i] = (floatx4){0.f, 0.f, 0.f, 0.f};
#pragma unroll
    for (int nt = 0; nt < 4; ++nt) {
      int rbk = nt * 16 + l16;
      accs[nt] = __builtin_amdgcn_mfma_f32_16x16x32_bf16(aq0, RD8(sK[ts], rbk, quad), accs[nt], 0, 0, 0);
      accs[nt] = __builtin_amdgcn_mfma_f32_16x16x32_bf16(aq1, RD8(sK[ts], rbk, 4 + quad), accs[nt], 0, 0, 0);
    }
    asm volatile("s_waitcnt lgkmcnt(0)" ::: "memory");   // WAR: prev ap reads done
    int prow = wave * 16 + quad * 4;
    if (!diag) {            // wave-uniform: no mask code on off-diagonal tiles
#pragma unroll
      for (int nt = 0; nt < 4; ++nt)
#pragma unroll
        for (int r = 0; r < 4; ++r) {
          float p = EXP2F(fminf(accs[nt][r], 108.f));
          sP[prow + r][nt * 16 + l16] = (u16)(__float_as_uint(p) >> 16);
        }
    } else {
      int qg_base = qX0 + prow;
#pragma unroll
      for (int nt = 0; nt < 4; ++nt) {
        int kg = k0 + nt * 16 + l16;
#pragma unroll
        for (int r = 0; r < 4; ++r) {
          float p = EXP2F(fminf(accs[nt][r], 108.f));
          if (kg > qg_base + r) p = 0.f;
          sP[prow + r][nt * 16 + l16] = (u16)(__float_as_uint(p) >> 16);
        }
      }
    }
    asm volatile("s_waitcnt lgkmcnt(0)" ::: "memory");   // stores visible (wave rows)
#pragma unroll
    for (int cst = 0; cst < 2; ++cst) {
      short8 ap = *(const short8*)&sP[wave * 16 + l16][cst * 32 + quad * 8];
#pragma unroll
      for (int dt = 0; dt < 4; ++dt) {
        int rv = dt * 16 + l16;
        acco[dt] = __builtin_amdgcn_mfma_f32_16x16x32_bf16(ap, RD8(sV[ts], rv, cst * 4 + quad), acco[dt], 0, 0, 0);
      }
      accsum = __builtin_amdgcn_mfma_f32_16x16x32_bf16(ap, ones, accsum, 0, 0, 0);
    }
  };

  int ktmaxL = 2 * qL + 1;                // tiles 0..ktmaxL; count 2qL+2 (even)
  for (int kt0 = 0; kt0 <= ktmaxL; kt0 += 2) {
    __syncthreads();   // prev pair's sK/sV (and sP ap) reads done in all waves
    stage_tile64(sK[0], &kbase[(size_t)kt0 * 64 * HD], HD, wave, lane);
    stage_tile64(sV[0], &vbase[(size_t)kt0 * 64], SEQ, wave, lane);
    stage_tile64(sK[1], &kbase[(size_t)(kt0 + 1) * 64 * HD], HD, wave, lane);
    stage_tile64(sV[1], &vbase[(size_t)(kt0 + 1) * 64], SEQ, wave, lane);
    __syncthreads();   // drains vmcnt -> both staged tiles visible

#pragma unroll
    for (int t = 0; t < 2; ++t) {
      int kt = kt0 + t;
      int k0 = kt * 64;
      if (kt <= 2 * qS)
        process(aqSA0, aqSA1, sA0, kt == 2 * qS, t, accSA, sumSA, k0);
      if (kt <= 2 * qS + 1)
        process(aqSB0, aqSB1, sB0, kt == 2 * qS + 1, t, accSB, sumSB, k0);
      if (kt <= 2 * qL)
        process(aqLA0, aqLA1, lA0, kt == 2 * qL, t, accLA, sumLA, k0);
      if (kt <= ktmaxL)
        process(aqLB0, aqLB1, lB0, kt == ktmaxL, t, accLB, sumLB, k0);
    }
  }

  // normalize + write [B,S,E], all four sub-tiles
  auto writeo = [&](int base, floatx4* acco, floatx4& accsum) {
#pragma unroll
    for (int dt = 0; dt < 4; ++dt)
#pragma unroll
      for (int r = 0; r < 4; ++r) {
        int rowoff = wave * 16 + quad * 4 + r;
        int col = h * HD + dt * 16 + l16;
        o[((size_t)b * SEQ + base + rowoff) * EMB + col] = f2bf(acco[dt][r] / accsum[r]);
      }
  };
  writeo(sA0, accSA, sumSA);
  writeo(sB0, accSB, sumSB);
  writeo(lA0, accLA, sumLA);
  writeo(lB0, accLB, sumLB);
}

// ---------------- output head: out[m] = x[m,:] . W_out + b_out (fp32 out) ---
__global__ __launch_bounds__(256) void out_proj(const u16* __restrict__ x,
                                                const float* __restrict__ wout,
                                                const float* __restrict__ bout,
                                                float* __restrict__ out) {
  int wave = threadIdx.x >> 6, lane = threadIdx.x & 63;
  int m = blockIdx.x * 4 + wave;
  union { uint4 vv; u16 s[8]; } xv;
  xv.vv = *(const uint4*)&x[(size_t)m * EMB + lane * 8];
  float4 w0 = *(const float4*)&wout[lane * 8];
  float4 w1 = *(const float4*)&wout[lane * 8 + 4];
  float wv[8] = {w0.x, w0.y, w0.z, w0.w, w1.x, w1.y, w1.z, w1.w};
  float s = 0.f;
#pragma unroll
  for (int j = 0; j < 8; ++j) s += bf2f(xv.s[j]) * wv[j];
#pragma unroll
  for (int sh = 1; sh < 64; sh <<= 1) s += __shfl_xor(s, sh, 64);
  if (lane == 0) out[m] = s + bout[0];
}

extern "C" void kernel_launch(void* const* d_in, const int* in_sizes, int n_in,
                              void* d_out, int out_size, void* d_ws, size_t ws_size,
                              hipStream_t stream) {
  const int*   inp   = (const int*)d_in[0];
  const float* table = (const float*)d_in[1];
  const float* Wq    = (const float*)d_in[2];
  const float* bq    = (const float*)d_in[3];
  const float* Wk    = (const float*)d_in[4];
  const float* bk    = (const float*)d_in[5];
  const float* Wv    = (const float*)d_in[6];
  const float* bv    = (const float*)d_in[7];
  const float* Wo    = (const float*)d_in[8];
  const float* bo    = (const float*)d_in[9];
  const float* Wout  = (const float*)d_in[10];
  const float* bout  = (const float*)d_in[11];
  float* outp = (float*)d_out;

  char* ws = (char*)d_ws;
  const size_t SZ = (size_t)M_ROWS * EMB * 2;  // 32 MB
  u16* x      = (u16*)(ws);
  u16* qb     = (u16*)(ws + SZ);
  u16* kb     = (u16*)(ws + 2 * SZ);
  u16* vb     = (u16*)(ws + 3 * SZ);   // [B,H,D,S]
  u16* attn_b = (u16*)(ws + 4 * SZ);
  u16* WtQKV  = (u16*)(ws + 5 * SZ);
  u16* WtO    = (u16*)(ws + 5 * SZ + (size_t)NLAYER * 3 * EMB * EMB * 2);
  float* pe   = (float*)(ws + 5 * SZ + (size_t)NLAYER * 4 * EMB * EMB * 2);  // 2 MB

  prep_weights<<<8192, 256, 0, stream>>>(Wq, Wk, Wv, Wo, WtQKV, WtO);
  pe_table<<<2048, 256, 0, stream>>>(pe);
  embed_pe<<<M_ROWS, 256, 0, stream>>>(inp, table, pe, x);

  for (int l = 0; l < NLAYER; ++l) {
    gemm_bt<<<3072, 256, 0, stream>>>(
        x, WtQKV + (size_t)l * 3 * EMB * EMB, EMB, /*mode=*/0,
        bq + l * EMB, bk + l * EMB, bv + l * EMB, qb, kb, vb, nullptr, 0);
    attn_kernel<<<1024, 256, 0, stream>>>(qb, kb, vb, attn_b);
    gemm_bt<<<1024, 256, 0, stream>>>(
        attn_b, WtO + (size_t)l * EMB * EMB, EMB, /*mode=*/1,
        bo + l * EMB, nullptr, nullptr, x, nullptr, nullptr, x, EMB);
  }
  out_proj<<<8192, 256, 0, stream>>>(x, Wout, bout, outp);
}

// Round 12
// 562.725 us; speedup vs baseline: 1.1416x; 1.1416x over previous
//
#include <hip/hip_runtime.h>

typedef unsigned short u16;
typedef unsigned int u32;
using short8  = __attribute__((ext_vector_type(8))) short;
using floatx4 = __attribute__((ext_vector_type(4))) float;

#define NB 32
#define SEQ 1024
#define EMB 512
#define NH 8
#define HD 64
#define NLAYER 2
#define M_ROWS (NB * SEQ)   // 32768

__device__ __forceinline__ float bf2f(u16 u) {
  union { u32 i; float f; } v; v.i = ((u32)u) << 16; return v.f;
}
__device__ __forceinline__ u16 f2bf(float f) {
  union { float f; u32 i; } v; v.f = f;
  u32 r = v.i + 0x7fffu + ((v.i >> 16) & 1u);
  return (u16)(r >> 16);
}
// packed f32x2 -> bf16x2 (RNE, same as f2bf). lo16 = cvt(a), hi16 = cvt(b).
__device__ __forceinline__ u32 cvtpk(float a, float b) {
  u32 r;
  asm volatile("v_cvt_pk_bf16_f32 %0, %1, %2" : "=v"(r) : "v"(a), "v"(b));
  return r;
}

#if __has_builtin(__builtin_amdgcn_exp2f)
#define EXP2F __builtin_amdgcn_exp2f
#else
#define EXP2F exp2f
#endif

// async global->LDS, 16B per lane. LDS dest = wave-uniform base + lane*16.
typedef __attribute__((address_space(3))) unsigned int lds_u32_t;
typedef __attribute__((address_space(1))) const unsigned int gbl_u32_t;
__device__ __forceinline__ void gload16(void* lds, const void* g) {
  gbl_u32_t* gp = (gbl_u32_t*)(unsigned long long)g;
  lds_u32_t* lp = (lds_u32_t*)(unsigned int)(unsigned long long)lds;
  __builtin_amdgcn_global_load_lds(gp, lp, 16, 0, 0);
}

// ---------------- weight pre-transpose + fp32->bf16: W[K,N] -> Bt[N,K] ------
__global__ void prep_weights(const float* __restrict__ Wq, const float* __restrict__ Wk,
                             const float* __restrict__ Wv, const float* __restrict__ Wo,
                             u16* __restrict__ WtQKV, u16* __restrict__ WtO) {
  int idx = blockIdx.x * 256 + threadIdx.x;
  const int QKV_TOT = NLAYER * 3 * EMB * EMB;
  if (idx < QKV_TOT) {
    int l = idx / (3 * EMB * EMB);
    int rem = idx % (3 * EMB * EMB);
    int n = rem / EMB, kk = rem % EMB;
    int w = n >> 9, e = n & 511;
    const float* src = (w == 0) ? Wq : (w == 1) ? Wk : Wv;
    WtQKV[idx] = f2bf(src[((size_t)l * EMB + kk) * EMB + e]);
  } else {
    int j = idx - QKV_TOT;
    int l = j / (EMB * EMB);
    int rem = j % (EMB * EMB);
    int n = rem / EMB, kk = rem % EMB;
    WtO[j] = f2bf(Wo[((size_t)l * EMB + kk) * EMB + n]);
  }
}

// ---------------- positional-encoding table: pe[s][e], f32 ------------------
// Hoists 16.7M on-device trig ops out of embed_pe (Appendix B: trig-heavy
// elementwise -> precompute table). 524288 elems = 2048 x 256 exact.
__global__ void pe_table(float* __restrict__ pe) {
  int idx = blockIdx.x * 256 + threadIdx.x;
  int s = idx >> 9, e = idx & 511;
  int i = e >> 1;
  const float negln = -9.210340371976184f / (float)EMB;
  float dt = __expf((float)(2 * i) * negln);
  float ang = (float)s * dt;
  pe[idx] = (e & 1) ? __cosf(ang) : __sinf(ang);
}

// ---------------- embedding + PE add (gather + add + pack, no trig) ---------
__global__ void embed_pe(const int* __restrict__ inp, const float* __restrict__ table,
                         const float* __restrict__ pe, u16* __restrict__ x) {
  int row = blockIdx.x;
  int tok = inp[row];
  int s = row & (SEQ - 1);
  int e = threadIdx.x * 2;
  float2 tv = *(const float2*)&table[(size_t)tok * EMB + e];
  float2 pv = *(const float2*)&pe[(size_t)s * EMB + e];
  *(u32*)&x[(size_t)row * EMB + e] = cvtpk(tv.x + pv.x, tv.y + pv.y);
}

// ---------------- GEMM: C[M,N] = A[M,K] @ Bt[N,K]^T + bias ------------------
// FROZEN r5/r9 state (verified best). 128x128, 3 LDS buffers, 2-deep
// prefetch, vmcnt(8) steady state. MfmaUtil pinned ~20% across 4 schedule
// variants (1-deep, 2-deep, zero-barrier, wide-tile); the only known escape
// (8-phase 256² swizzled schedule) is a sync-structure rewrite, disqualified
// headless after r7's graph-replay race.
// mode 0: N=1536 (NT=12). Q (*0.125*log2e folded: attn uses exp2), K ->
//         [B,H,S,D]; V (bn0>=1024): operand-swapped MFMA -> [B,H,D,S].
// mode 1: N=512 (NT=4),  x = x + relu(C + bias)  (in place, out0 == resid)
#define BK 32

__global__ __launch_bounds__(256) void gemm_bt(
    const u16* __restrict__ A, const u16* __restrict__ Bt, int K, int mode,
    const float* bias0, const float* bias1, const float* bias2,
    u16* out0, u16* out1, u16* out2, const u16* resid, int Nstride) {
  __shared__ u16 sA[3][128][BK];
  __shared__ u16 sB[3][128][BK];
  int tid = threadIdx.x;
  int wave = tid >> 6, lane = tid & 63;
  int quad = lane >> 4, l16 = lane & 15;
  int wm = wave >> 1, wn = wave & 1;

  int NT = (mode == 0) ? 12 : 4;          // N-tiles per M-tile
  int blk = blockIdx.x;
  int xcd = blk & 7, slot = blk >> 3;
  int mtl = slot / NT, ntl = slot % NT;   // 32 M-tiles per XCD, N-tiles inner
  int bm0 = (xcd * 32 + mtl) * 128;
  int bn0 = ntl * 128;
  bool vswap = (mode == 0) && (bn0 >= 1024);

  floatx4 acc[4][4];
#pragma unroll
  for (int i = 0; i < 4; ++i)
#pragma unroll
    for (int j = 0; j < 4; ++j) acc[i][j] = (floatx4){0.f, 0.f, 0.f, 0.f};

  int rb = wave * 32;                         // wave stages rows rb..rb+31
  int lrow = lane >> 2;                       // 0..15
  int gcg = ((lane & 3) ^ ((lane >> 3) & 3)) * 8;  // fetch chunk for slot lane&3
  int rsl = (quad ^ ((l16 >> 1) & 3)) * 8;    // read slot holding chunk `quad`

  const u16* Arow0 = &A[(size_t)(bm0 + rb + lrow) * K + gcg];
  const u16* Arow1 = &A[(size_t)(bm0 + rb + 16 + lrow) * K + gcg];
  const u16* Brow0 = &Bt[(size_t)(bn0 + rb + lrow) * K + gcg];
  const u16* Brow1 = &Bt[(size_t)(bn0 + rb + 16 + lrow) * K + gcg];

  // prologue: stage k-tiles 0,1 into buffers 0,1 (niter is always 16 here)
  gload16(&sA[0][rb][0],      Arow0);
  gload16(&sA[0][rb + 16][0], Arow1);
  gload16(&sB[0][rb][0],      Brow0);
  gload16(&sB[0][rb + 16][0], Brow1);
  gload16(&sA[1][rb][0],      Arow0 + BK);
  gload16(&sA[1][rb + 16][0], Arow1 + BK);
  gload16(&sB[1][rb][0],      Brow0 + BK);
  gload16(&sB[1][rb + 16][0], Brow1 + BK);

  const int niter = K / BK;
  int c0 = 0, c1 = 1, c2 = 2;   // c0 = compute buf, c2 = stage target
  for (int it = 0; it < niter; ++it) {
    if (it + 2 < niter) {
      int k2 = (it + 2) * BK;
      gload16(&sA[c2][rb][0],      Arow0 + k2);
      gload16(&sA[c2][rb + 16][0], Arow1 + k2);
      gload16(&sB[c2][rb][0],      Brow0 + k2);
      gload16(&sB[c2][rb + 16][0], Brow1 + k2);
      asm volatile("s_waitcnt vmcnt(8)" ::: "memory");  // tile `it` complete
    } else if (it + 1 < niter) {
      asm volatile("s_waitcnt vmcnt(4)" ::: "memory");  // tile `it` complete
    } else {
      asm volatile("s_waitcnt vmcnt(0)" ::: "memory");
    }
    asm volatile("s_barrier" ::: "memory");             // buf ready for all

    short8 af[4], bfr[4];
#pragma unroll
    for (int mi = 0; mi < 4; ++mi)
      af[mi] = *(const short8*)&sA[c0][wm * 64 + mi * 16 + l16][rsl];
#pragma unroll
    for (int ni = 0; ni < 4; ++ni)
      bfr[ni] = *(const short8*)&sB[c0][wn * 64 + ni * 16 + l16][rsl];
    if (!vswap) {
#pragma unroll
      for (int mi = 0; mi < 4; ++mi)
#pragma unroll
        for (int ni = 0; ni < 4; ++ni)
          acc[mi][ni] = __builtin_amdgcn_mfma_f32_16x16x32_bf16(af[mi], bfr[ni], acc[mi][ni], 0, 0, 0);
    } else {
#pragma unroll
      for (int mi = 0; mi < 4; ++mi)
#pragma unroll
        for (int ni = 0; ni < 4; ++ni)
          acc[mi][ni] = __builtin_amdgcn_mfma_f32_16x16x32_bf16(bfr[ni], af[mi], acc[mi][ni], 0, 0, 0);
    }
    asm volatile("s_waitcnt lgkmcnt(0)" ::: "memory");  // all ds_reads complete
    asm volatile("s_barrier" ::: "memory");             // before buf overwrite
    int t = c0; c0 = c1; c1 = c2; c2 = t;
  }

  // ---- epilogue: wave-private LDS repack -> coalesced 128B dword-row stores
  u16* scr = ((u16*)sA) + wave * (16 * 68);
  int erow = lane >> 5;            // 0..1: row within a read pass
  int dcol = lane & 31;            // dword column (2 bf16 per dword)

  if (!vswap) {
    int w = bn0 >> 9;                                   // 0=Q, 1=K (mode 0)
    const float* bp = (mode == 1) ? bias0 : ((w == 0) ? bias0 : bias1);
    // Q: fold 1/sqrt(D) AND log2(e) so attn can use v_exp_f32 (exp2) directly
    float sc = (mode == 0 && w == 0) ? 0.18033688011112042f : 1.0f;
    float bvs[4];
#pragma unroll
    for (int ni = 0; ni < 4; ++ni)
      bvs[ni] = bp[(bn0 + wn * 64 + ni * 16 + l16) & 511] * sc;

    int colg = bn0 + wn * 64 + dcol * 2;
#pragma unroll
    for (int mi = 0; mi < 4; ++mi) {
#pragma unroll
      for (int ni = 0; ni < 4; ++ni) {
        float t0 = fmaf(acc[mi][ni][0], sc, bvs[ni]);
        float t1 = fmaf(acc[mi][ni][1], sc, bvs[ni]);
        float t2 = fmaf(acc[mi][ni][2], sc, bvs[ni]);
        float t3 = fmaf(acc[mi][ni][3], sc, bvs[ni]);
        if (mode == 1) {
          t0 = fmaxf(t0, 0.f); t1 = fmaxf(t1, 0.f);
          t2 = fmaxf(t2, 0.f); t3 = fmaxf(t3, 0.f);
        }
        u32 p01 = cvtpk(t0, t1), p23 = cvtpk(t2, t3);
        int base = (quad * 4) * 68 + ni * 16 + l16;
        scr[base]       = (u16)p01;
        scr[base + 68]  = (u16)(p01 >> 16);
        scr[base + 136] = (u16)p23;
        scr[base + 204] = (u16)(p23 >> 16);
      }
      asm volatile("s_waitcnt lgkmcnt(0)" ::: "memory");  // wave-private: no barrier

      int m0 = bm0 + wm * 64 + mi * 16;
      if (mode == 0) {
        // Q/K store: [B,H,S,D]; rows m0..m0+15 share b,h; sid,addr linear in row
        int e = colg & 511, hh = e >> 6, dd = e & 63;
        int bb = m0 >> 10, sid0 = m0 & 1023;
        u16* optr = (w == 0) ? out0 : out1;
        u16* op = &optr[((size_t)(bb * NH + hh) * SEQ + sid0) * HD + dd];
#pragma unroll
        for (int p = 0; p < 8; ++p) {
          int row = p * 2 + erow;
          u32 d2 = *(const u32*)&scr[row * 68 + dcol * 2];
          *(u32*)&op[(size_t)row * HD] = d2;
        }
      } else {
        size_t off0 = (size_t)m0 * Nstride + colg;
        const u16* rp = &resid[off0];
        u16* wp = &out0[off0];
#pragma unroll
        for (int p = 0; p < 8; ++p) {
          int row = p * 2 + erow;
          u32 d2 = *(const u32*)&scr[row * 68 + dcol * 2];
          u32 rs = *(const u32*)&rp[(size_t)row * Nstride];
          float lo = bf2f((u16)d2) + bf2f((u16)rs);
          float hi = bf2f((u16)(d2 >> 16)) + bf2f((u16)(rs >> 16));
          *(u32*)&wp[(size_t)row * Nstride] = cvtpk(lo, hi);
        }
      }
      asm volatile("s_waitcnt lgkmcnt(0)" ::: "memory");  // reads done before rewrite
    }
  } else {
    // V section: D rows = weight rows (d), D cols = x rows (sid)
    float bvv[4][4];
#pragma unroll
    for (int ni = 0; ni < 4; ++ni)
#pragma unroll
      for (int r = 0; r < 4; ++r)
        bvv[ni][r] = bias2[(bn0 + wn * 64 + ni * 16 + quad * 4 + r) & 511];

    int b = (bm0 + wm * 64) >> 10;
    int sid0 = (bm0 + wm * 64) & 1023;
    int n0 = bn0 + wn * 64;
    int h = (n0 >> 6) & 7;
#pragma unroll
    for (int ni = 0; ni < 4; ++ni) {
#pragma unroll
      for (int mi = 0; mi < 4; ++mi) {
        float t0 = acc[mi][ni][0] + bvv[ni][0];
        float t1 = acc[mi][ni][1] + bvv[ni][1];
        float t2 = acc[mi][ni][2] + bvv[ni][2];
        float t3 = acc[mi][ni][3] + bvv[ni][3];
        u32 p01 = cvtpk(t0, t1), p23 = cvtpk(t2, t3);
        int base = (quad * 4) * 68 + mi * 16 + l16;
        scr[base]       = (u16)p01;
        scr[base + 68]  = (u16)(p01 >> 16);
        scr[base + 136] = (u16)p23;
        scr[base + 204] = (u16)(p23 >> 16);
      }
      asm volatile("s_waitcnt lgkmcnt(0)" ::: "memory");

      int d0 = (n0 & 63) + ni * 16;
      u16* op2 = &out2[((size_t)(b * NH + h) * HD + d0) * SEQ + sid0 + dcol * 2];
#pragma unroll
      for (int p = 0; p < 8; ++p) {
        int row = p * 2 + erow;
        u32 d2 = *(const u32*)&scr[row * 68 + dcol * 2];
        *(u32*)&op2[(size_t)row * SEQ] = d2;
      }
      asm volatile("s_waitcnt lgkmcnt(0)" ::: "memory");
    }
  }
}

// ---------------- flash attention, causal ----------------------------------
// FROZEN r5/r9 state (verified best). Uniform work pairing: each block runs
// jobs qtp = pr then 7-pr sequentially (exactly 18 k-iters/block, zero size
// variance), grid 1024, single-buffered K/V staging, dedicated sQ + sP[2],
// light-first job order. r10/r11 merged-loop variants regressed (VGPR 100->
// 132 cut occupancy; 2-tile batching scaled the vmcnt drain with bytes).
// Q pre-scaled by 0.125*log2e so p = exp2(s); causal cndmasks only on the
// wave-uniform diagonal tile.
__device__ __forceinline__ void stage_tile64(u16 (*dst)[64], const u16* g, int gstride,
                                             int wave, int lane) {
  int r = lane >> 3;
  int gcg = ((lane & 7) ^ r) * 8;
#pragma unroll
  for (int c = 0; c < 2; ++c) {
    int row0 = (wave * 2 + c) * 8;
    gload16(&dst[row0][0], &g[(size_t)(row0 + r) * gstride + gcg]);
  }
}
#define RD8(T, row, cg) (*(const short8*)&T[row][(((cg) ^ ((row) & 7)) * 8)])

__global__ __launch_bounds__(256) void attn_kernel(
    const u16* __restrict__ q, const u16* __restrict__ k, const u16* __restrict__ vt,
    u16* __restrict__ o) {
  int blk = blockIdx.x;          // 0..1023
  int xcd = blk & 7, slot = blk >> 3;    // slot 0..127
  int bh = xcd * 32 + (slot >> 2);       // 4 pair-blocks per bh, same XCD
  int pr = slot & 3;                     // pair index: jobs qtp=pr, 7-pr
  int b = bh >> 3, h = bh & 7;
  __shared__ u16 sQ[128][64], sK[64][64], sV[64][64];
  __shared__ u16 sP[2][64][68];
  int tid = threadIdx.x, wave = tid >> 6, lane = tid & 63;
  int quad = lane >> 4, l16 = lane & 15;

  const u16* kbase = &k[(size_t)bh * SEQ * HD];
  const u16* vbase = &vt[(size_t)bh * HD * SEQ];

  short8 ones;
#pragma unroll
  for (int j = 0; j < 8; ++j) ones[j] = (short)0x3F80;   // bf16 1.0

  for (int job = 0; job < 2; ++job) {
    int qtp = job ? (7 - pr) : pr;       // light first, heavy second
    int qA0 = qtp * 128, qB0 = qA0 + 64;

    // stage this job's Q (sQ region idle: prior job's hoist long done)
    stage_tile64((u16(*)[64])&sQ[0][0],  &q[((size_t)bh * SEQ + qA0) * HD], HD, wave, lane);
    stage_tile64((u16(*)[64])&sQ[64][0], &q[((size_t)bh * SEQ + qB0) * HD], HD, wave, lane);

    floatx4 accoA[4], accoB[4], accsumA, accsumB;
#pragma unroll
    for (int i = 0; i < 4; ++i) {
      accoA[i] = (floatx4){0.f, 0.f, 0.f, 0.f};
      accoB[i] = (floatx4){0.f, 0.f, 0.f, 0.f};
    }
    accsumA = (floatx4){0.f, 0.f, 0.f, 0.f};
    accsumB = (floatx4){0.f, 0.f, 0.f, 0.f};
    short8 aqA0 = {}, aqA1 = {}, aqB0 = {}, aqB1 = {};

    // one sub-tile pass: S = Q@K^T (pre-scaled incl. log2e), p = exp2(s)
    // (masked->0), P->LDS->A-layout, PV + ones-MFMA row sums.
    auto process = [&](short8 aq0, short8 aq1, int qX0, bool diag, int sub,
                       floatx4* acco, floatx4& accsum, int k0) {
      floatx4 accs[4];
#pragma unroll
      for (int i = 0; i < 4; ++i) accs[i] = (floatx4){0.f, 0.f, 0.f, 0.f};
#pragma unroll
      for (int nt = 0; nt < 4; ++nt) {
        int rbk = nt * 16 + l16;
        accs[nt] = __builtin_amdgcn_mfma_f32_16x16x32_bf16(aq0, RD8(sK, rbk, quad), accs[nt], 0, 0, 0);
        accs[nt] = __builtin_amdgcn_mfma_f32_16x16x32_bf16(aq1, RD8(sK, rbk, 4 + quad), accs[nt], 0, 0, 0);
      }
      int prow = wave * 16 + quad * 4;
      if (!diag) {            // wave-uniform: no mask code on off-diagonal tiles
#pragma unroll
        for (int nt = 0; nt < 4; ++nt)
#pragma unroll
          for (int r = 0; r < 4; ++r) {
            float p = EXP2F(fminf(accs[nt][r], 108.f));
            sP[sub][prow + r][nt * 16 + l16] = (u16)(__float_as_uint(p) >> 16);
          }
      } else {
        int qg_base = qX0 + prow;
#pragma unroll
        for (int nt = 0; nt < 4; ++nt) {
          int kg = k0 + nt * 16 + l16;
#pragma unroll
          for (int r = 0; r < 4; ++r) {
            float p = EXP2F(fminf(accs[nt][r], 108.f));
            if (kg > qg_base + r) p = 0.f;
            sP[sub][prow + r][nt * 16 + l16] = (u16)(__float_as_uint(p) >> 16);
          }
        }
      }
      asm volatile("s_waitcnt lgkmcnt(0)" ::: "memory");   // wave-private rows
#pragma unroll
      for (int cst = 0; cst < 2; ++cst) {
        short8 ap = *(const short8*)&sP[sub][wave * 16 + l16][cst * 32 + quad * 8];
#pragma unroll
        for (int dt = 0; dt < 4; ++dt) {
          int rv = dt * 16 + l16;
          acco[dt] = __builtin_amdgcn_mfma_f32_16x16x32_bf16(ap, RD8(sV, rv, cst * 4 + quad), acco[dt], 0, 0, 0);
        }
        accsum = __builtin_amdgcn_mfma_f32_16x16x32_bf16(ap, ones, accsum, 0, 0, 0);
      }
    };

    int ktmax = 2 * qtp + 1;
    for (int kt = 0; kt <= ktmax; ++kt) {
      int k0 = kt * 64;
      __syncthreads();   // prev iter's sK/sV reads done (covers job boundary too)
      stage_tile64(sK, &kbase[(size_t)k0 * HD], HD, wave, lane);
      stage_tile64(sV, &vbase[k0], SEQ, wave, lane);
      __syncthreads();   // drains vmcnt -> staged K/V (and this job's sQ) visible

      if (kt == 0) {     // hoist Q fragments (wave-private rows of sQ)
        int ra = wave * 16 + l16;
        aqA0 = RD8(sQ, ra, quad);
        aqA1 = RD8(sQ, ra, 4 + quad);
        int rb_ = 64 + wave * 16 + l16;
        aqB0 = RD8(sQ, rb_, quad);
        aqB1 = RD8(sQ, rb_, 4 + quad);
      }

      if (kt <= 2 * qtp)
        process(aqA0, aqA1, qA0, kt == 2 * qtp, 0, accoA, accsumA, k0);
      process(aqB0, aqB1, qB0, kt == ktmax, 1, accoB, accsumB, k0);
    }

    // normalize + write [B,S,E], both sub-tiles of this job
#pragma unroll
    for (int dt = 0; dt < 4; ++dt)
#pragma unroll
      for (int r = 0; r < 4; ++r) {
        int rowoff = wave * 16 + quad * 4 + r;
        int col = h * HD + dt * 16 + l16;
        o[((size_t)b * SEQ + qA0 + rowoff) * EMB + col] = f2bf(accoA[dt][r] / accsumA[r]);
        o[((size_t)b * SEQ + qB0 + rowoff) * EMB + col] = f2bf(accoB[dt][r] / accsumB[r]);
      }
  }
}

// ---------------- output head: out[m] = x[m,:] . W_out + b_out (fp32 out) ---
__global__ __launch_bounds__(256) void out_proj(const u16* __restrict__ x,
                                                const float* __restrict__ wout,
                                                const float* __restrict__ bout,
                                                float* __restrict__ out) {
  int wave = threadIdx.x >> 6, lane = threadIdx.x & 63;
  int m = blockIdx.x * 4 + wave;
  union { uint4 vv; u16 s[8]; } xv;
  xv.vv = *(const uint4*)&x[(size_t)m * EMB + lane * 8];
  float4 w0 = *(const float4*)&wout[lane * 8];
  float4 w1 = *(const float4*)&wout[lane * 8 + 4];
  float wv[8] = {w0.x, w0.y, w0.z, w0.w, w1.x, w1.y, w1.z, w1.w};
  float s = 0.f;
#pragma unroll
  for (int j = 0; j < 8; ++j) s += bf2f(xv.s[j]) * wv[j];
#pragma unroll
  for (int sh = 1; sh < 64; sh <<= 1) s += __shfl_xor(s, sh, 64);
  if (lane == 0) out[m] = s + bout[0];
}

extern "C" void kernel_launch(void* const* d_in, const int* in_sizes, int n_in,
                              void* d_out, int out_size, void* d_ws, size_t ws_size,
                              hipStream_t stream) {
  const int*   inp   = (const int*)d_in[0];
  const float* table = (const float*)d_in[1];
  const float* Wq    = (const float*)d_in[2];
  const float* bq    = (const float*)d_in[3];
  const float* Wk    = (const float*)d_in[4];
  const float* bk    = (const float*)d_in[5];
  const float* Wv    = (const float*)d_in[6];
  const float* bv    = (const float*)d_in[7];
  const float* Wo    = (const float*)d_in[8];
  const float* bo    = (const float*)d_in[9];
  const float* Wout  = (const float*)d_in[10];
  const float* bout  = (const float*)d_in[11];
  float* outp = (float*)d_out;

  char* ws = (char*)d_ws;
  const size_t SZ = (size_t)M_ROWS * EMB * 2;  // 32 MB
  u16* x      = (u16*)(ws);
  u16* qb     = (u16*)(ws + SZ);
  u16* kb     = (u16*)(ws + 2 * SZ);
  u16* vb     = (u16*)(ws + 3 * SZ);   // [B,H,D,S]
  u16* attn_b = (u16*)(ws + 4 * SZ);
  u16* WtQKV  = (u16*)(ws + 5 * SZ);
  u16* WtO    = (u16*)(ws + 5 * SZ + (size_t)NLAYER * 3 * EMB * EMB * 2);
  float* pe   = (float*)(ws + 5 * SZ + (size_t)NLAYER * 4 * EMB * EMB * 2);  // 2 MB

  prep_weights<<<8192, 256, 0, stream>>>(Wq, Wk, Wv, Wo, WtQKV, WtO);
  pe_table<<<2048, 256, 0, stream>>>(pe);
  embed_pe<<<M_ROWS, 256, 0, stream>>>(inp, table, pe, x);

  for (int l = 0; l < NLAYER; ++l) {
    gemm_bt<<<3072, 256, 0, stream>>>(
        x, WtQKV + (size_t)l * 3 * EMB * EMB, EMB, /*mode=*/0,
        bq + l * EMB, bk + l * EMB, bv + l * EMB, qb, kb, vb, nullptr, 0);
    attn_kernel<<<1024, 256, 0, stream>>>(qb, kb, vb, attn_b);
    gemm_bt<<<1024, 256, 0, stream>>>(
        attn_b, WtO + (size_t)l * EMB * EMB, EMB, /*mode=*/1,
        bo + l * EMB, nullptr, nullptr, x, nullptr, nullptr, x, EMB);
  }
  out_proj<<<8192, 256, 0, stream>>>(x, Wout, bout, outp);
}